// Round 1
// baseline (2857.310 us; speedup 1.0000x reference)
//
#include <hip/hip_runtime.h>

#define N_NODES 100000
#define N_EDGES 1600000
#define DIN 128
#define DOUT 128
#define N_SUP 2

// ---------------------------------------------------------------------------
// Kernel 1: init out[n][o] = bias[o]  (so SpMM atomics can accumulate on top)
// ---------------------------------------------------------------------------
__global__ __launch_bounds__(256) void init_out_kernel(float* __restrict__ out,
                                                       const float* __restrict__ bias) {
    const int idx = blockIdx.x * 256 + threadIdx.x;             // float4 index
    const int total = N_NODES * DOUT / 4;                       // 3.2M
    if (idx < total) {
        const float4 b = ((const float4*)bias)[idx & (DOUT / 4 - 1)];
        ((float4*)out)[idx] = b;
    }
}

// ---------------------------------------------------------------------------
// Kernel 2: pre[s] = x @ w[s]   x:[N,128] fp32, w[s]:[128,128] fp32
// Block: 256 threads (16 tx x 16 ty). Tile: 128 rows x 128 cols.
// Per-thread 8x8 register tile. x staged transposed in LDS ([k][row]),
// w streamed from global (64KB/support -> L1/L2 resident).
// ---------------------------------------------------------------------------
__global__ __launch_bounds__(256) void gemm_kernel(const float* __restrict__ x,
                                                   const float* __restrict__ w,
                                                   float* __restrict__ pre) {
    __shared__ float xT[DIN][128];   // [k][row], 64 KB
    const int s = blockIdx.y;
    const int row0 = blockIdx.x * 128;
    const int t = threadIdx.x;

    // Load x tile transposed. Thread t: row r = t>>1, k-half = (t&1)*64.
    {
        const int r = t >> 1;
        const int kh = (t & 1) * 64;
        const int gr = row0 + r;
        const float* xp = x + (size_t)gr * DIN + kh;
        #pragma unroll
        for (int kk = 0; kk < 64; kk += 4) {
            float4 v = make_float4(0.f, 0.f, 0.f, 0.f);
            if (gr < N_NODES) v = *(const float4*)(xp + kk);
            xT[kh + kk + 0][r] = v.x;
            xT[kh + kk + 1][r] = v.y;
            xT[kh + kk + 2][r] = v.z;
            xT[kh + kk + 3][r] = v.w;
        }
    }
    __syncthreads();

    const int tx = t & 15;   // col group: cols tx*8 .. tx*8+7
    const int ty = t >> 4;   // row group: rows ty*8 .. ty*8+7
    const float* wp = w + (size_t)s * DIN * DOUT + tx * 8;

    float acc[8][8];
    #pragma unroll
    for (int i = 0; i < 8; i++)
        #pragma unroll
        for (int j = 0; j < 8; j++) acc[i][j] = 0.f;

    #pragma unroll 2
    for (int k = 0; k < DIN; k++) {
        const float4 xa = *(const float4*)&xT[k][ty * 8];
        const float4 xb = *(const float4*)&xT[k][ty * 8 + 4];
        const float4 wa = *(const float4*)(wp + (size_t)k * DOUT);
        const float4 wb = *(const float4*)(wp + (size_t)k * DOUT + 4);
        const float xv[8] = {xa.x, xa.y, xa.z, xa.w, xb.x, xb.y, xb.z, xb.w};
        const float wv[8] = {wa.x, wa.y, wa.z, wa.w, wb.x, wb.y, wb.z, wb.w};
        #pragma unroll
        for (int i = 0; i < 8; i++)
            #pragma unroll
            for (int j = 0; j < 8; j++)
                acc[i][j] += xv[i] * wv[j];
    }

    #pragma unroll
    for (int i = 0; i < 8; i++) {
        const int gr = row0 + ty * 8 + i;
        if (gr < N_NODES) {
            float* op = pre + ((size_t)s * N_NODES + gr) * DOUT + tx * 8;
            *(float4*)op       = make_float4(acc[i][0], acc[i][1], acc[i][2], acc[i][3]);
            *(float4*)(op + 4) = make_float4(acc[i][4], acc[i][5], acc[i][6], acc[i][7]);
        }
    }
}

// ---------------------------------------------------------------------------
// Kernel 3: SpMM scatter. One wave per edge; lane handles features 2l,2l+1.
// out[rows[e]] += vals[e] * pre[s][cols[e]]
// ---------------------------------------------------------------------------
__global__ __launch_bounds__(256) void spmm_kernel(const float* __restrict__ pre,
                                                   const float* __restrict__ vals,
                                                   const int* __restrict__ rows,
                                                   const int* __restrict__ cols,
                                                   float* __restrict__ out) {
    const int lane = threadIdx.x & 63;
    const int wid = threadIdx.x >> 6;
    const int e = blockIdx.x * 4 + wid;            // edge index within support
    if (e >= N_EDGES) return;
    const int s = blockIdx.y;

    const size_t se = (size_t)s * N_EDGES + e;
    const float v = vals[se];
    const int r = rows[se];
    const int c = cols[se];

    const float2 p = *(const float2*)(pre + ((size_t)s * N_NODES + c) * DOUT + lane * 2);
    float* op = out + (size_t)r * DOUT + lane * 2;
    unsafeAtomicAdd(op,     v * p.x);
    unsafeAtomicAdd(op + 1, v * p.y);
}

// ---------------------------------------------------------------------------
// Kernel 4: in-place ReLU on out
// ---------------------------------------------------------------------------
__global__ __launch_bounds__(256) void relu_kernel(float* __restrict__ out) {
    const int idx = blockIdx.x * 256 + threadIdx.x;   // float4 index
    const int total = N_NODES * DOUT / 4;
    if (idx < total) {
        float4 v = ((float4*)out)[idx];
        v.x = fmaxf(v.x, 0.f);
        v.y = fmaxf(v.y, 0.f);
        v.z = fmaxf(v.z, 0.f);
        v.w = fmaxf(v.w, 0.f);
        ((float4*)out)[idx] = v;
    }
}

extern "C" void kernel_launch(void* const* d_in, const int* in_sizes, int n_in,
                              void* d_out, int out_size, void* d_ws, size_t ws_size,
                              hipStream_t stream) {
    (void)in_sizes; (void)n_in; (void)out_size; (void)ws_size;
    const float* x        = (const float*)d_in[0];   // [N, 128]
    const float* w        = (const float*)d_in[1];   // [2, 128, 128]
    const float* bias     = (const float*)d_in[2];   // [128]
    const float* sup_vals = (const float*)d_in[3];   // [2, E]
    const int*   sup_rows = (const int*)d_in[4];     // [2, E]
    const int*   sup_cols = (const int*)d_in[5];     // [2, E]
    float* out = (float*)d_out;                      // [N, 128]
    float* pre = (float*)d_ws;                       // [2, N, 128] = 102.4 MB

    // 1. out = bias (broadcast)
    {
        const int total4 = N_NODES * DOUT / 4;
        init_out_kernel<<<(total4 + 255) / 256, 256, 0, stream>>>(out, bias);
    }
    // 2. pre[s] = x @ w[s]
    {
        dim3 grid((N_NODES + 127) / 128, N_SUP);
        gemm_kernel<<<grid, 256, 0, stream>>>(x, w, pre);
    }
    // 3. scatter-accumulate edges
    {
        dim3 grid((N_EDGES + 3) / 4, N_SUP);
        spmm_kernel<<<grid, 256, 0, stream>>>(pre, sup_vals, sup_rows, sup_cols, out);
    }
    // 4. ReLU
    {
        const int total4 = N_NODES * DOUT / 4;
        relu_kernel<<<(total4 + 255) / 256, 256, 0, stream>>>(out);
    }
}

// Round 2
// 860.737 us; speedup vs baseline: 3.3196x; 3.3196x over previous
//
#include <hip/hip_runtime.h>

#define N_NODES 100000
#define N_EDGES 1600000
#define DIN 128
#define DOUT 128
#define N_SUP 2
#define E_TOT (N_SUP * N_EDGES)          // 3,200,000
#define SCAN_CHUNK 1024                   // elems per scan1 block
#define NBLK_SCAN ((N_NODES + SCAN_CHUNK - 1) / SCAN_CHUNK)   // 98

// ---------------------------------------------------------------------------
// Kernel: pre[s] = x @ w[s]   (fp32 vector-ALU GEMM, 8x8 per-thread tile)
// ---------------------------------------------------------------------------
__global__ __launch_bounds__(256) void gemm_kernel(const float* __restrict__ x,
                                                   const float* __restrict__ w,
                                                   float* __restrict__ pre) {
    __shared__ float xT[DIN][128];   // [k][row], 64 KB
    const int s = blockIdx.y;
    const int row0 = blockIdx.x * 128;
    const int t = threadIdx.x;

    {
        const int r = t >> 1;
        const int kh = (t & 1) * 64;
        const int gr = row0 + r;
        const float* xp = x + (size_t)gr * DIN + kh;
        #pragma unroll
        for (int kk = 0; kk < 64; kk += 4) {
            float4 v = make_float4(0.f, 0.f, 0.f, 0.f);
            if (gr < N_NODES) v = *(const float4*)(xp + kk);
            xT[kh + kk + 0][r] = v.x;
            xT[kh + kk + 1][r] = v.y;
            xT[kh + kk + 2][r] = v.z;
            xT[kh + kk + 3][r] = v.w;
        }
    }
    __syncthreads();

    const int tx = t & 15;
    const int ty = t >> 4;
    const float* wp = w + (size_t)s * DIN * DOUT + tx * 8;

    float acc[8][8];
    #pragma unroll
    for (int i = 0; i < 8; i++)
        #pragma unroll
        for (int j = 0; j < 8; j++) acc[i][j] = 0.f;

    #pragma unroll 2
    for (int k = 0; k < DIN; k++) {
        const float4 xa = *(const float4*)&xT[k][ty * 8];
        const float4 xb = *(const float4*)&xT[k][ty * 8 + 4];
        const float4 wa = *(const float4*)(wp + (size_t)k * DOUT);
        const float4 wb = *(const float4*)(wp + (size_t)k * DOUT + 4);
        const float xv[8] = {xa.x, xa.y, xa.z, xa.w, xb.x, xb.y, xb.z, xb.w};
        const float wv[8] = {wa.x, wa.y, wa.z, wa.w, wb.x, wb.y, wb.z, wb.w};
        #pragma unroll
        for (int i = 0; i < 8; i++)
            #pragma unroll
            for (int j = 0; j < 8; j++)
                acc[i][j] += xv[i] * wv[j];
    }

    #pragma unroll
    for (int i = 0; i < 8; i++) {
        const int gr = row0 + ty * 8 + i;
        if (gr < N_NODES) {
            float* op = pre + ((size_t)s * N_NODES + gr) * DOUT + tx * 8;
            *(float4*)op       = make_float4(acc[i][0], acc[i][1], acc[i][2], acc[i][3]);
            *(float4*)(op + 4) = make_float4(acc[i][4], acc[i][5], acc[i][6], acc[i][7]);
        }
    }
}

// ---------------------------------------------------------------------------
// CSR build: zero counts -> histogram -> 3-kernel exclusive scan -> scatter
// ---------------------------------------------------------------------------
__global__ __launch_bounds__(256) void zero_kernel(int* __restrict__ cnt) {
    const int i = blockIdx.x * 256 + threadIdx.x;
    if (i < N_NODES) cnt[i] = 0;
}

__global__ __launch_bounds__(256) void hist_kernel(const int* __restrict__ rows,
                                                   int* __restrict__ cnt) {
    const int i = blockIdx.x * 256 + threadIdx.x;   // flat edge id over [2,E]
    if (i < E_TOT) atomicAdd(&cnt[rows[i]], 1);
}

__global__ __launch_bounds__(256) void scan1_kernel(const int* __restrict__ cnt,
                                                    int* __restrict__ row_start,
                                                    int* __restrict__ bsums) {
    __shared__ int sdata[256];
    const int t = threadIdx.x;
    const int base = blockIdx.x * SCAN_CHUNK + t * 4;
    int v[4];
    int sum = 0;
    #pragma unroll
    for (int j = 0; j < 4; j++) {
        const int idx = base + j;
        v[j] = (idx < N_NODES) ? cnt[idx] : 0;
        sum += v[j];
    }
    sdata[t] = sum;
    __syncthreads();
    #pragma unroll
    for (int off = 1; off < 256; off <<= 1) {
        const int val = (t >= off) ? sdata[t - off] : 0;
        __syncthreads();
        sdata[t] += val;
        __syncthreads();
    }
    int run = sdata[t] - sum;    // exclusive prefix of this thread's chunk
    #pragma unroll
    for (int j = 0; j < 4; j++) {
        const int idx = base + j;
        if (idx < N_NODES) row_start[idx] = run;
        run += v[j];
    }
    if (t == 255) bsums[blockIdx.x] = sdata[255];
}

__global__ void scan2_kernel(int* __restrict__ bsums) {
    if (threadIdx.x == 0 && blockIdx.x == 0) {
        int run = 0;
        for (int i = 0; i < NBLK_SCAN; i++) {
            const int v = bsums[i];
            bsums[i] = run;
            run += v;
        }
    }
}

__global__ __launch_bounds__(256) void scan3_kernel(int* __restrict__ row_start,
                                                    int* __restrict__ cursor,
                                                    const int* __restrict__ bsums) {
    const int i = blockIdx.x * 256 + threadIdx.x;
    if (i < N_NODES) {
        const int v = row_start[i] + bsums[i / SCAN_CHUNK];
        row_start[i] = v;
        cursor[i] = v;
    }
    if (i == 0) row_start[N_NODES] = E_TOT;
}

// scatter edge (col_eff, val) pairs into CSR order
__global__ __launch_bounds__(256) void scatter_kernel(const int* __restrict__ rows,
                                                      const int* __restrict__ cols,
                                                      const float* __restrict__ vals,
                                                      int* __restrict__ cursor,
                                                      int2* __restrict__ edata) {
    const int i = blockIdx.x * 256 + threadIdx.x;   // flat edge id
    if (i >= E_TOT) return;
    const int r = rows[i];
    const int pos = atomicAdd(&cursor[r], 1);
    const int c_eff = cols[i] + ((i >= N_EDGES) ? N_NODES : 0);  // index into pre[s*N+c]
    edata[pos] = make_int2(c_eff, __float_as_int(vals[i]));
}

// ---------------------------------------------------------------------------
// Gather-accumulate: one wave per output row, lane l handles features 2l,2l+1.
// Fuses bias + ReLU. No atomics.
// ---------------------------------------------------------------------------
__global__ __launch_bounds__(256) void gather_kernel(const float* __restrict__ pre,
                                                     const int2* __restrict__ edata,
                                                     const int* __restrict__ row_start,
                                                     const float* __restrict__ bias,
                                                     float* __restrict__ out) {
    const int lane = threadIdx.x & 63;
    const int wid = threadIdx.x >> 6;
    const int row = blockIdx.x * 4 + wid;
    if (row >= N_NODES) return;

    const int beg = row_start[row];
    const int end = row_start[row + 1];
    const int fo = lane * 2;

    float ax = 0.f, ay = 0.f;
    int e = beg;
    for (; e + 4 <= end; e += 4) {
        const int2 d0 = edata[e];
        const int2 d1 = edata[e + 1];
        const int2 d2 = edata[e + 2];
        const int2 d3 = edata[e + 3];
        const float2 p0 = *(const float2*)(pre + (size_t)d0.x * DOUT + fo);
        const float2 p1 = *(const float2*)(pre + (size_t)d1.x * DOUT + fo);
        const float2 p2 = *(const float2*)(pre + (size_t)d2.x * DOUT + fo);
        const float2 p3 = *(const float2*)(pre + (size_t)d3.x * DOUT + fo);
        const float v0 = __int_as_float(d0.y);
        const float v1 = __int_as_float(d1.y);
        const float v2 = __int_as_float(d2.y);
        const float v3 = __int_as_float(d3.y);
        ax = fmaf(v0, p0.x, ax); ay = fmaf(v0, p0.y, ay);
        ax = fmaf(v1, p1.x, ax); ay = fmaf(v1, p1.y, ay);
        ax = fmaf(v2, p2.x, ax); ay = fmaf(v2, p2.y, ay);
        ax = fmaf(v3, p3.x, ax); ay = fmaf(v3, p3.y, ay);
    }
    for (; e < end; e++) {
        const int2 d = edata[e];
        const float2 p = *(const float2*)(pre + (size_t)d.x * DOUT + fo);
        const float v = __int_as_float(d.y);
        ax = fmaf(v, p.x, ax);
        ay = fmaf(v, p.y, ay);
    }

    const float2 b = *(const float2*)(bias + fo);
    float2 r;
    r.x = fmaxf(ax + b.x, 0.f);
    r.y = fmaxf(ay + b.y, 0.f);
    *(float2*)(out + (size_t)row * DOUT + fo) = r;
}

extern "C" void kernel_launch(void* const* d_in, const int* in_sizes, int n_in,
                              void* d_out, int out_size, void* d_ws, size_t ws_size,
                              hipStream_t stream) {
    (void)in_sizes; (void)n_in; (void)out_size; (void)ws_size;
    const float* x        = (const float*)d_in[0];   // [N, 128]
    const float* w        = (const float*)d_in[1];   // [2, 128, 128]
    const float* bias     = (const float*)d_in[2];   // [128]
    const float* sup_vals = (const float*)d_in[3];   // [2, E] flat
    const int*   sup_rows = (const int*)d_in[4];     // [2, E] flat
    const int*   sup_cols = (const int*)d_in[5];     // [2, E] flat
    float* out = (float*)d_out;                      // [N, 128]

    // ws layout (4-byte units)
    char* ws = (char*)d_ws;
    float* pre      = (float*)ws;                                   // 2*N*128 = 102,400,000 B
    int2*  edata    = (int2*)(ws + (size_t)N_SUP * N_NODES * DOUT * 4);   // 3.2M * 8 = 25.6 MB
    int*   row_start= (int*)((char*)edata + (size_t)E_TOT * 8);     // (N+1)*4
    int*   cursor   = row_start + (N_NODES + 1);                    // N*4
    int*   bsums    = cursor + N_NODES;                             // 98*4

    // 1. GEMM: pre[s] = x @ w[s]
    {
        dim3 grid((N_NODES + 127) / 128, N_SUP);
        gemm_kernel<<<grid, 256, 0, stream>>>(x, w, pre);
    }
    // 2. CSR build
    zero_kernel<<<(N_NODES + 255) / 256, 256, 0, stream>>>(cursor);          // cursor = counts
    hist_kernel<<<(E_TOT + 255) / 256, 256, 0, stream>>>(sup_rows, cursor);
    scan1_kernel<<<NBLK_SCAN, 256, 0, stream>>>(cursor, row_start, bsums);
    scan2_kernel<<<1, 64, 0, stream>>>(bsums);
    scan3_kernel<<<(N_NODES + 255) / 256, 256, 0, stream>>>(row_start, cursor, bsums);
    scatter_kernel<<<(E_TOT + 255) / 256, 256, 0, stream>>>(sup_rows, sup_cols, sup_vals,
                                                            cursor, edata);
    // 3. Gather-accumulate + bias + ReLU
    gather_kernel<<<(N_NODES + 3) / 4, 256, 0, stream>>>(pre, edata, row_start, bias, out);
}

// Round 3
// 848.334 us; speedup vs baseline: 3.3681x; 1.0146x over previous
//
#include <hip/hip_runtime.h>

#define N_NODES 100000
#define N_EDGES 1600000
#define DIN 128
#define DOUT 128
#define N_SUP 2
#define E_TOT (N_SUP * N_EDGES)          // 3,200,000
#define SCAN_CHUNK 1024                   // elems per scan1 block
#define NBLK_SCAN ((N_NODES + SCAN_CHUNK - 1) / SCAN_CHUNK)   // 98

typedef float f32x2 __attribute__((ext_vector_type(2)));
typedef float f32x4 __attribute__((ext_vector_type(4)));
typedef int   i32x2 __attribute__((ext_vector_type(2)));

// ---------------------------------------------------------------------------
// Kernel: pre[s] = x @ w[s]   (fp32 vector-ALU GEMM, 8x8 per-thread tile)
// x reads + pre writes are non-temporal (streamed once) to keep L2 clean.
// ---------------------------------------------------------------------------
__global__ __launch_bounds__(256) void gemm_kernel(const float* __restrict__ x,
                                                   const float* __restrict__ w,
                                                   float* __restrict__ pre) {
    __shared__ float xT[DIN][128];   // [k][row], 64 KB
    const int s = blockIdx.y;
    const int row0 = blockIdx.x * 128;
    const int t = threadIdx.x;

    {
        const int r = t >> 1;
        const int kh = (t & 1) * 64;
        const int gr = row0 + r;
        const float* xp = x + (size_t)gr * DIN + kh;
        #pragma unroll
        for (int kk = 0; kk < 64; kk += 4) {
            f32x4 v = {0.f, 0.f, 0.f, 0.f};
            if (gr < N_NODES) v = __builtin_nontemporal_load((const f32x4*)(xp + kk));
            xT[kh + kk + 0][r] = v.x;
            xT[kh + kk + 1][r] = v.y;
            xT[kh + kk + 2][r] = v.z;
            xT[kh + kk + 3][r] = v.w;
        }
    }
    __syncthreads();

    const int tx = t & 15;
    const int ty = t >> 4;
    const float* wp = w + (size_t)s * DIN * DOUT + tx * 8;

    float acc[8][8];
    #pragma unroll
    for (int i = 0; i < 8; i++)
        #pragma unroll
        for (int j = 0; j < 8; j++) acc[i][j] = 0.f;

    #pragma unroll 2
    for (int k = 0; k < DIN; k++) {
        const float4 xa = *(const float4*)&xT[k][ty * 8];
        const float4 xb = *(const float4*)&xT[k][ty * 8 + 4];
        const float4 wa = *(const float4*)(wp + (size_t)k * DOUT);
        const float4 wb = *(const float4*)(wp + (size_t)k * DOUT + 4);
        const float xv[8] = {xa.x, xa.y, xa.z, xa.w, xb.x, xb.y, xb.z, xb.w};
        const float wv[8] = {wa.x, wa.y, wa.z, wa.w, wb.x, wb.y, wb.z, wb.w};
        #pragma unroll
        for (int i = 0; i < 8; i++)
            #pragma unroll
            for (int j = 0; j < 8; j++)
                acc[i][j] += xv[i] * wv[j];
    }

    #pragma unroll
    for (int i = 0; i < 8; i++) {
        const int gr = row0 + ty * 8 + i;
        if (gr < N_NODES) {
            float* op = pre + ((size_t)s * N_NODES + gr) * DOUT + tx * 8;
            f32x4 a = {acc[i][0], acc[i][1], acc[i][2], acc[i][3]};
            f32x4 b = {acc[i][4], acc[i][5], acc[i][6], acc[i][7]};
            __builtin_nontemporal_store(a, (f32x4*)op);
            __builtin_nontemporal_store(b, (f32x4*)(op + 4));
        }
    }
}

// ---------------------------------------------------------------------------
// CSR build: memset counts -> histogram -> 3-kernel exclusive scan -> scatter
// ---------------------------------------------------------------------------
__global__ __launch_bounds__(256) void hist_kernel(const int* __restrict__ rows,
                                                   int* __restrict__ cnt) {
    const int i = blockIdx.x * 256 + threadIdx.x;   // flat edge id over [2,E]
    if (i < E_TOT) atomicAdd(&cnt[__builtin_nontemporal_load(rows + i)], 1);
}

__global__ __launch_bounds__(256) void scan1_kernel(const int* __restrict__ cnt,
                                                    int* __restrict__ row_start,
                                                    int* __restrict__ bsums) {
    __shared__ int sdata[256];
    const int t = threadIdx.x;
    const int base = blockIdx.x * SCAN_CHUNK + t * 4;
    int v[4];
    int sum = 0;
    #pragma unroll
    for (int j = 0; j < 4; j++) {
        const int idx = base + j;
        v[j] = (idx < N_NODES) ? cnt[idx] : 0;
        sum += v[j];
    }
    sdata[t] = sum;
    __syncthreads();
    #pragma unroll
    for (int off = 1; off < 256; off <<= 1) {
        const int val = (t >= off) ? sdata[t - off] : 0;
        __syncthreads();
        sdata[t] += val;
        __syncthreads();
    }
    int run = sdata[t] - sum;    // exclusive prefix of this thread's chunk
    #pragma unroll
    for (int j = 0; j < 4; j++) {
        const int idx = base + j;
        if (idx < N_NODES) row_start[idx] = run;
        run += v[j];
    }
    if (t == 255) bsums[blockIdx.x] = sdata[255];
}

__global__ __launch_bounds__(128) void scan2_kernel(int* __restrict__ bsums) {
    __shared__ int s[128];
    const int t = threadIdx.x;
    const int v = (t < NBLK_SCAN) ? bsums[t] : 0;
    s[t] = v;
    __syncthreads();
    #pragma unroll
    for (int off = 1; off < 128; off <<= 1) {
        const int u = (t >= off) ? s[t - off] : 0;
        __syncthreads();
        s[t] += u;
        __syncthreads();
    }
    if (t < NBLK_SCAN) bsums[t] = s[t] - v;   // exclusive
}

__global__ __launch_bounds__(256) void scan3_kernel(int* __restrict__ row_start,
                                                    int* __restrict__ cursor,
                                                    const int* __restrict__ bsums) {
    const int i = blockIdx.x * 256 + threadIdx.x;
    if (i < N_NODES) {
        const int v = row_start[i] + bsums[i / SCAN_CHUNK];
        row_start[i] = v;
        cursor[i] = v;
    }
    if (i == 0) row_start[N_NODES] = E_TOT;
}

// scatter edge (col_eff, val) pairs into CSR order.
// Streaming reads are non-temporal so the random edata lines can stay
// dirty-resident in L2 and merge (16 x 8B writes per 64B line).
__global__ __launch_bounds__(256) void scatter_kernel(const int* __restrict__ rows,
                                                      const int* __restrict__ cols,
                                                      const float* __restrict__ vals,
                                                      int* __restrict__ cursor,
                                                      i32x2* __restrict__ edata) {
    const int i = blockIdx.x * 256 + threadIdx.x;   // flat edge id
    if (i >= E_TOT) return;
    const int r = __builtin_nontemporal_load(rows + i);
    const int c = __builtin_nontemporal_load(cols + i);
    const float v = __builtin_nontemporal_load(vals + i);
    const int pos = atomicAdd(&cursor[r], 1);
    i32x2 d;
    d.x = c + ((i >= N_EDGES) ? N_NODES : 0);       // index into pre[s*N+c]
    d.y = __float_as_int(v);
    edata[pos] = d;                                  // cached store -> L2 merge
}

// ---------------------------------------------------------------------------
// Gather-accumulate: one wave per output row, lane l handles features 2l,2l+1.
// Fuses bias + ReLU. No atomics. edata stream + out store are non-temporal.
// ---------------------------------------------------------------------------
__global__ __launch_bounds__(256) void gather_kernel(const float* __restrict__ pre,
                                                     const i32x2* __restrict__ edata,
                                                     const int* __restrict__ row_start,
                                                     const float* __restrict__ bias,
                                                     float* __restrict__ out) {
    const int lane = threadIdx.x & 63;
    const int wid = threadIdx.x >> 6;
    const int row = blockIdx.x * 4 + wid;
    if (row >= N_NODES) return;

    const int beg = row_start[row];
    const int end = row_start[row + 1];
    const int fo = lane * 2;

    float ax = 0.f, ay = 0.f;
    int e = beg;
    for (; e + 4 <= end; e += 4) {
        const i32x2 d0 = __builtin_nontemporal_load(edata + e);
        const i32x2 d1 = __builtin_nontemporal_load(edata + e + 1);
        const i32x2 d2 = __builtin_nontemporal_load(edata + e + 2);
        const i32x2 d3 = __builtin_nontemporal_load(edata + e + 3);
        const float2 p0 = *(const float2*)(pre + (size_t)d0.x * DOUT + fo);
        const float2 p1 = *(const float2*)(pre + (size_t)d1.x * DOUT + fo);
        const float2 p2 = *(const float2*)(pre + (size_t)d2.x * DOUT + fo);
        const float2 p3 = *(const float2*)(pre + (size_t)d3.x * DOUT + fo);
        const float v0 = __int_as_float(d0.y);
        const float v1 = __int_as_float(d1.y);
        const float v2 = __int_as_float(d2.y);
        const float v3 = __int_as_float(d3.y);
        ax = fmaf(v0, p0.x, ax); ay = fmaf(v0, p0.y, ay);
        ax = fmaf(v1, p1.x, ax); ay = fmaf(v1, p1.y, ay);
        ax = fmaf(v2, p2.x, ax); ay = fmaf(v2, p2.y, ay);
        ax = fmaf(v3, p3.x, ax); ay = fmaf(v3, p3.y, ay);
    }
    for (; e < end; e++) {
        const i32x2 d = __builtin_nontemporal_load(edata + e);
        const float2 p = *(const float2*)(pre + (size_t)d.x * DOUT + fo);
        const float v = __int_as_float(d.y);
        ax = fmaf(v, p.x, ax);
        ay = fmaf(v, p.y, ay);
    }

    const float2 b = *(const float2*)(bias + fo);
    f32x2 r;
    r.x = fmaxf(ax + b.x, 0.f);
    r.y = fmaxf(ay + b.y, 0.f);
    __builtin_nontemporal_store(r, (f32x2*)(out + (size_t)row * DOUT + fo));
}

extern "C" void kernel_launch(void* const* d_in, const int* in_sizes, int n_in,
                              void* d_out, int out_size, void* d_ws, size_t ws_size,
                              hipStream_t stream) {
    (void)in_sizes; (void)n_in; (void)out_size; (void)ws_size;
    const float* x        = (const float*)d_in[0];   // [N, 128]
    const float* w        = (const float*)d_in[1];   // [2, 128, 128]
    const float* bias     = (const float*)d_in[2];   // [128]
    const float* sup_vals = (const float*)d_in[3];   // [2, E] flat
    const int*   sup_rows = (const int*)d_in[4];     // [2, E] flat
    const int*   sup_cols = (const int*)d_in[5];     // [2, E] flat
    float* out = (float*)d_out;                      // [N, 128]

    // ws layout
    char* ws = (char*)d_ws;
    float* pre      = (float*)ws;                                   // 2*N*128*4 = 102.4 MB
    i32x2* edata    = (i32x2*)(ws + (size_t)N_SUP * N_NODES * DOUT * 4);  // 3.2M*8 = 25.6 MB
    int*   row_start= (int*)((char*)edata + (size_t)E_TOT * 8);     // (N+1)*4
    int*   cursor   = row_start + (N_NODES + 1);                    // N*4
    int*   bsums    = cursor + N_NODES;                             // 98*4

    // 1. GEMM: pre[s] = x @ w[s]
    {
        dim3 grid((N_NODES + 127) / 128, N_SUP);
        gemm_kernel<<<grid, 256, 0, stream>>>(x, w, pre);
    }
    // 2. CSR build
    hipMemsetAsync(cursor, 0, N_NODES * sizeof(int), stream);       // cursor = counts
    hist_kernel<<<(E_TOT + 255) / 256, 256, 0, stream>>>(sup_rows, cursor);
    scan1_kernel<<<NBLK_SCAN, 256, 0, stream>>>(cursor, row_start, bsums);
    scan2_kernel<<<1, 128, 0, stream>>>(bsums);
    scan3_kernel<<<(N_NODES + 255) / 256, 256, 0, stream>>>(row_start, cursor, bsums);
    scatter_kernel<<<(E_TOT + 255) / 256, 256, 0, stream>>>(sup_rows, sup_cols, sup_vals,
                                                            cursor, edata);
    // 3. Gather-accumulate + bias + ReLU
    gather_kernel<<<(N_NODES + 3) / 4, 256, 0, stream>>>(pre, edata, row_start, bias, out);
}